// Round 2
// baseline (13714.758 us; speedup 1.0000x reference)
//
#include <hip/hip_runtime.h>
#include <hip/hip_bf16.h>

#define Hd 512
#define Bd 512
#define Vd 128
#define Sd 256

__device__ __forceinline__ float sigf(float v) { return 1.0f / (1.0f + __expf(-v)); }
__device__ __forceinline__ float tanhfast(float v) { return 1.0f - 2.0f / (__expf(2.0f * v) + 1.0f); }

// Build wxt[dir][v][g*H+u] = Wx[g][u][v] + bx[g][u] + bh[g][u]  (2 x 128 x 2048 floats)
__global__ __launch_bounds__(256) void prep_wxt(
    const float* __restrict__ WxF, const float* __restrict__ bxF, const float* __restrict__ bhF,
    const float* __restrict__ WxB, const float* __restrict__ bxB, const float* __restrict__ bhB,
    float* __restrict__ wxt) {
  int e = blockIdx.x * 256 + threadIdx.x;   // 0 .. 524287
  int dir = e >> 18;                        // V*4H = 262144
  int r = e & 262143;
  int v = r >> 11;                          // 4H = 2048
  int gh = r & 2047;
  int g = gh >> 9;
  int u = gh & 511;
  const float* Wx = dir ? WxB : WxF;
  const float* bx = dir ? bxB : bxF;
  const float* bh = dir ? bhB : bhF;
  wxt[e] = Wx[(g * Hd + u) * Vd + v] + bx[gh] + bh[gh];
}

// Zero n float4's starting at p (n*4 floats).
__global__ __launch_bounds__(256) void init_zero(float* __restrict__ p) {
  int e = blockIdx.x * 256 + threadIdx.x;
  float4 z; z.x = 0.f; z.y = 0.f; z.z = 0.f; z.w = 0.f;
  ((float4*)p)[e] = z;
}

// out[b,s,v] = bfc[v] for all (b,s). 16384 blocks x 256 (float4 per thread).
__global__ __launch_bounds__(256) void init_out(const float* __restrict__ bfc,
                                                float* __restrict__ out) {
  int e = blockIdx.x * 256 + threadIdx.x;     // float4 index
  int v0 = (e & 31) * 4;                      // 128 v / 4 per float4
  ((float4*)out)[e] = *(const float4*)&bfc[v0];
}

// One LSTM step for both directions + fused FC accumulation of the PREVIOUS h.
// grid = (16, 8, 3), 256 thr.
//   z in {0,1}: direction z LSTM step. x = ktile (32 k), y = btile (64 b).
//   z == 2: FC accumulate: out[b, t_dir, v] += Wfc_dir . hprev_dir[b,:]
//           x: dir = x>>3, vtile = x&7 (16 v). y = btile (64 b). Skipped at s==0.
// s ranges 0..Sd; at s==Sd only the FC plane runs (flush of last h).
__global__ __launch_bounds__(256) void lstm_step(
    const float* __restrict__ wxt, const int* __restrict__ x,
    const float* __restrict__ WhF, const float* __restrict__ WhB,
    const float* __restrict__ hprev, float* __restrict__ hnext,
    float* __restrict__ cst, const float* __restrict__ Wfc,
    float* __restrict__ out, int s) {
  __shared__ float hT[32][68];       // [kk][b]  (transposed)
  __shared__ float wT[32][33][4];    // [kk][k][g]
  __shared__ float wf[32][17];       // [kk][v]  (FC plane)
  const int tid = threadIdx.x;

  if (blockIdx.z == 2) {
    // ---------------- FC accumulate plane ----------------
    if (s == 0) return;
    const int dir = blockIdx.x >> 3;
    const int v0 = (blockIdx.x & 7) * 16;
    const int t = dir ? (Sd - s) : (s - 1);
    const float* __restrict__ hp = hprev + dir * (Bd * Hd);
    const int b0 = blockIdx.y * 64;
    const int tx = tid & 15;         // v
    const int ty = tid >> 4;         // b group (4 rows each)
    float fa[4] = {0.f, 0.f, 0.f, 0.f};
    for (int hc = 0; hc < Hd; hc += 32) {
#pragma unroll
      for (int i = 0; i < 2; ++i) {
        int f = i * 256 + tid;
        int r = f >> 3, c4 = (f & 7) * 4;
        float4 v = *(const float4*)&hp[(b0 + r) * Hd + hc + c4];
        hT[c4 + 0][r] = v.x; hT[c4 + 1][r] = v.y; hT[c4 + 2][r] = v.z; hT[c4 + 3][r] = v.w;
      }
#pragma unroll
      for (int i = 0; i < 2; ++i) {
        int e = i * 256 + tid;       // 0..511
        int kk = e & 31, v = e >> 5; // v 0..15
        wf[kk][v] = Wfc[(v0 + v) * 1024 + dir * 512 + hc + kk];
      }
      __syncthreads();
#pragma unroll
      for (int kk = 0; kk < 32; ++kk) {
        float4 hv = *(const float4*)&hT[kk][ty * 4];
        float w = wf[kk][tx];
        fa[0] += hv.x * w; fa[1] += hv.y * w; fa[2] += hv.z * w; fa[3] += hv.w * w;
      }
      __syncthreads();
    }
#pragma unroll
    for (int i = 0; i < 4; ++i) {
      int b = b0 + ty * 4 + i;
      size_t idx = ((size_t)b * Sd + t) * Vd + v0 + tx;
      out[idx] += fa[i];
    }
    return;
  }

  // ---------------- LSTM step plane ----------------
  if (s >= Sd) return;               // flush-only dispatch
  const int dir = blockIdx.z;
  const int t = dir ? (Sd - 1 - s) : s;
  const float* __restrict__ Wh = dir ? WhB : WhF;
  const float* __restrict__ hp = hprev + dir * (Bd * Hd);
  float* hn = hnext + dir * (Bd * Hd);
  float* cc = cst + dir * (Bd * Hd);
  const int k0 = blockIdx.x * 32;
  const int b0 = blockIdx.y * 64;
  const int tx = tid & 15;
  const int ty = tid >> 4;

  float acc[4][4][2];
#pragma unroll
  for (int g = 0; g < 4; ++g)
#pragma unroll
    for (int i = 0; i < 4; ++i) {
      acc[g][i][0] = 0.f; acc[g][i][1] = 0.f;
    }

  for (int hc = 0; hc < Hd; hc += 32) {
#pragma unroll
    for (int i = 0; i < 2; ++i) {
      int f = i * 256 + tid;
      int r = f >> 3, c4 = (f & 7) * 4;
      float4 v = *(const float4*)&hp[(b0 + r) * Hd + hc + c4];
      hT[c4 + 0][r] = v.x; hT[c4 + 1][r] = v.y; hT[c4 + 2][r] = v.z; hT[c4 + 3][r] = v.w;
    }
#pragma unroll
    for (int i = 0; i < 4; ++i) {
      int f = i * 256 + tid;
      int row = f >> 3, c4 = (f & 7) * 4;
      int g = row >> 5, kk = row & 31;
      float4 v = *(const float4*)&Wh[(g * Hd + k0 + kk) * Hd + hc + c4];
      wT[c4 + 0][kk][g] = v.x; wT[c4 + 1][kk][g] = v.y; wT[c4 + 2][kk][g] = v.z; wT[c4 + 3][kk][g] = v.w;
    }
    __syncthreads();
#pragma unroll 8
    for (int hh = 0; hh < 32; ++hh) {
      float4 hv = *(const float4*)&hT[hh][ty * 4];
      float4 w0 = *(const float4*)&wT[hh][tx * 2 + 0][0];
      float4 w1 = *(const float4*)&wT[hh][tx * 2 + 1][0];
#pragma unroll
      for (int ib = 0; ib < 4; ++ib) {
        float hvb = (&hv.x)[ib];
        acc[0][ib][0] += hvb * w0.x; acc[1][ib][0] += hvb * w0.y;
        acc[2][ib][0] += hvb * w0.z; acc[3][ib][0] += hvb * w0.w;
        acc[0][ib][1] += hvb * w1.x; acc[1][ib][1] += hvb * w1.y;
        acc[2][ib][1] += hvb * w1.z; acc[3][ib][1] += hvb * w1.w;
      }
    }
    __syncthreads();
  }

#pragma unroll
  for (int ib = 0; ib < 4; ++ib) {
    int b = b0 + ty * 4 + ib;
    int xv = x[b * Sd + t];
    const float* wrow = &wxt[(size_t)(dir * Vd + xv) * 2048];
#pragma unroll
    for (int ik = 0; ik < 2; ++ik) {
      int k = k0 + tx * 2 + ik;
      float gi = sigf(acc[0][ib][ik] + wrow[k]);
      float gf = sigf(acc[1][ib][ik] + wrow[512 + k]);
      float go = sigf(acc[2][ib][ik] + wrow[1024 + k]);
      float gg = tanhfast(acc[3][ib][ik] + wrow[1536 + k]);
      int idx = b * Hd + k;
      float cn = gf * cc[idx] + gi * gg;
      cc[idx] = cn;
      hn[idx] = go * tanhfast(cn);
    }
  }
}

extern "C" void kernel_launch(void* const* d_in, const int* in_sizes, int n_in,
                              void* d_out, int out_size, void* d_ws, size_t ws_size,
                              hipStream_t stream) {
  const int* x      = (const int*)d_in[0];
  const float* WxF  = (const float*)d_in[1];
  const float* WhF  = (const float*)d_in[2];
  const float* bxF  = (const float*)d_in[3];
  const float* bhF  = (const float*)d_in[4];
  const float* WxB  = (const float*)d_in[5];
  const float* WhB  = (const float*)d_in[6];
  const float* bxB  = (const float*)d_in[7];
  const float* bhB  = (const float*)d_in[8];
  const float* Wfc  = (const float*)d_in[9];
  const float* bfc  = (const float*)d_in[10];
  float* out = (float*)d_out;

  // ws layout (floats): wxt[524288] | h[2 phase][2 dir][B*H] | c[2 dir][B*H]
  // total = 2,097,152 floats = 8 MB
  float* ws = (float*)d_ws;
  float* wxt = ws;
  float* hbuf = ws + 524288;
  float* cbuf = ws + 1572864;

  prep_wxt<<<2048, 256, 0, stream>>>(WxF, bxF, bhF, WxB, bxB, bhB, wxt);
  // zero h (both phases) + c: 1,572,864 floats = 393,216 float4
  init_zero<<<1536, 256, 0, stream>>>(hbuf);
  // out = bias
  init_out<<<16384, 256, 0, stream>>>(bfc, out);

  for (int s = 0; s <= Sd; ++s) {
    int ph = s & 1;
    lstm_step<<<dim3(16, 8, 3), 256, 0, stream>>>(
        wxt, x, WhF, WhB,
        hbuf + (size_t)ph * 524288, hbuf + (size_t)(ph ^ 1) * 524288,
        cbuf, Wfc, out, s);
  }
}

// Round 3
// 4348.974 us; speedup vs baseline: 3.1536x; 3.1536x over previous
//
#include <hip/hip_runtime.h>
#include <hip/hip_bf16.h>

#define Hd 512
#define Bd 512
#define Vd 128
#define Sd 256

typedef _Float16 half8 __attribute__((ext_vector_type(8)));
typedef _Float16 half4v __attribute__((ext_vector_type(4)));
typedef float float4v __attribute__((ext_vector_type(4)));

__device__ __forceinline__ float sigf(float v) { return 1.0f / (1.0f + __expf(-v)); }
__device__ __forceinline__ float tanhfast(float v) { return 1.0f - 2.0f / (__expf(2.0f * v) + 1.0f); }

__device__ __forceinline__ void load_lds16(const void* g, void* l) {
  __builtin_amdgcn_global_load_lds(
      (const __attribute__((address_space(1))) unsigned int*)g,
      (__attribute__((address_space(3))) unsigned int*)l, 16, 0, 0);
}

// wxt[dir][v][n] = Wx[g][k][v] + bx[g*H+k] + bh[g*H+k], n = (k<<2)|g. fp32.
__global__ __launch_bounds__(256) void prep_wxt(
    const float* __restrict__ WxF, const float* __restrict__ bxF, const float* __restrict__ bhF,
    const float* __restrict__ WxB, const float* __restrict__ bxB, const float* __restrict__ bhB,
    float* __restrict__ wxt) {
  int e = blockIdx.x * 256 + threadIdx.x;   // 0..524287
  int n = e & 2047;
  int v = (e >> 11) & 127;
  int dir = e >> 18;
  int k = n >> 2, g = n & 3;
  const float* Wx = dir ? WxB : WxF;
  const float* bx = dir ? bxB : bxF;
  const float* bh = dir ? bhB : bhF;
  int gk = g * Hd + k;
  wxt[e] = Wx[gk * Vd + v] + bx[gk] + bh[gk];
}

// whr[dir][n][hc] f16 = Wh_dir[g][k][hc], n = (k<<2)|g
__global__ __launch_bounds__(256) void prep_wh16(
    const float* __restrict__ WhF, const float* __restrict__ WhB, _Float16* __restrict__ whr) {
  int e = blockIdx.x * 256 + threadIdx.x;   // 0..2097151
  int hc = e & 511;
  int n = (e >> 9) & 2047;
  int dir = e >> 20;
  int k = n >> 2, g = n & 3;
  const float* Wh = dir ? WhB : WhF;
  whr[e] = (_Float16)Wh[(g * Hd + k) * Hd + hc];
}

// wfc16[dir][v][hc] f16 = Wfc[v][dir*512+hc]
__global__ __launch_bounds__(256) void prep_wfc16(
    const float* __restrict__ Wfc, _Float16* __restrict__ wfc16) {
  int e = blockIdx.x * 256 + threadIdx.x;   // 0..131071
  int hc = e & 511;
  int v = (e >> 9) & 127;
  int dir = e >> 16;
  wfc16[e] = (_Float16)Wfc[v * 1024 + dir * 512 + hc];
}

__global__ __launch_bounds__(256) void init_zero(float* __restrict__ p) {
  int e = blockIdx.x * 256 + threadIdx.x;
  float4 z; z.x = 0.f; z.y = 0.f; z.z = 0.f; z.w = 0.f;
  ((float4*)p)[e] = z;
}

__global__ __launch_bounds__(256) void init_out(const float* __restrict__ bfc,
                                                float* __restrict__ out) {
  int e = blockIdx.x * 256 + threadIdx.x;
  int v0 = (e & 31) * 4;
  ((float4*)out)[e] = *(const float4*)&bfc[v0];
}

// One step, both dirs + fused FC of PREVIOUS h. grid = 136 blocks x 256 thr.
//   bid < 128 : LSTM MFMA. dir = bid>>6; mt = bid&3 (128 b); nt = (bid&63)>>2 (128 n).
//   bid >= 128: FC MFMA.   f = bid-128; dir = f>>2; mt = f&3. N = 128 v.
__global__ __launch_bounds__(256) void step_mfma(
    const float* __restrict__ wxt, const int* __restrict__ x,
    const _Float16* __restrict__ whr, const _Float16* __restrict__ wfc16,
    const _Float16* __restrict__ hprev, _Float16* __restrict__ hnext,
    float* __restrict__ cst, float* __restrict__ out, int s) {
  __shared__ _Float16 At[128 * 32];     // [b][hc]  8 KB
  __shared__ _Float16 Bt[128 * 32];     // [n][hc]  8 KB
  __shared__ _Float16 GT[128 * 136];    // [n][b pad] 34 KB (LSTM epilogue)
  const int tid = threadIdx.x;
  const int lane = tid & 63;
  const int w = tid >> 6;
  const int bid = blockIdx.x;

  bool isFC = (bid >= 128);
  int dir, mt, nt;
  if (isFC) { int f = bid - 128; dir = f >> 2; mt = f & 3; nt = 0; }
  else      { dir = bid >> 6; mt = bid & 3; nt = (bid & 63) >> 2; }
  if (isFC ? (s == 0) : (s >= Sd)) return;

  const int b0 = mt * 128;
  const _Float16* Asrc = hprev + dir * (Bd * Hd);
  const _Float16* Bsrc = isFC ? (wfc16 + dir * (128 * 512))
                              : (whr + ((size_t)dir * 2048 + nt * 128) * 512);

  float4v acc[4][4];
#pragma unroll
  for (int mi = 0; mi < 4; ++mi)
#pragma unroll
    for (int ni = 0; ni < 4; ++ni) acc[mi][ni] = (float4v)0.f;

  const int wm0 = (w & 1) * 64;
  const int wn0 = (w >> 1) * 64;
  const int lrow = lane >> 2;           // 0..15
  const int lcol = (lane & 3) * 16;     // byte offset in 64-B row

  for (int hc0 = 0; hc0 < Hd; hc0 += 32) {
#pragma unroll
    for (int i = 0; i < 2; ++i) {
      int r = w * 32 + i * 16 + lrow;
      load_lds16((const char*)Asrc + ((size_t)(b0 + r) * Hd + hc0) * 2 + lcol,
                 &At[(w * 32 + i * 16) * 32]);
      load_lds16((const char*)Bsrc + ((size_t)r * 512 + hc0) * 2 + lcol,
                 &Bt[(w * 32 + i * 16) * 32]);
    }
    __syncthreads();
    half8 af[4], bf[4];
#pragma unroll
    for (int mi = 0; mi < 4; ++mi)
      af[mi] = *(const half8*)&At[(wm0 + mi * 16 + (lane & 15)) * 32 + (lane >> 4) * 8];
#pragma unroll
    for (int ni = 0; ni < 4; ++ni)
      bf[ni] = *(const half8*)&Bt[(wn0 + ni * 16 + (lane & 15)) * 32 + (lane >> 4) * 8];
#pragma unroll
    for (int mi = 0; mi < 4; ++mi)
#pragma unroll
      for (int ni = 0; ni < 4; ++ni)
        acc[mi][ni] = __builtin_amdgcn_mfma_f32_16x16x32_f16(af[mi], bf[ni], acc[mi][ni], 0, 0, 0);
    __syncthreads();
  }

  if (isFC) {
    const int t = dir ? (Sd - s) : (s - 1);
#pragma unroll
    for (int mi = 0; mi < 4; ++mi) {
      int m = b0 + wm0 + mi * 16 + (lane >> 4) * 4;
#pragma unroll
      for (int ni = 0; ni < 4; ++ni) {
        int v = wn0 + ni * 16 + (lane & 15);
        size_t base = ((size_t)m * Sd + t) * Vd + v;
#pragma unroll
        for (int r2 = 0; r2 < 4; ++r2)
          out[base + (size_t)r2 * (Sd * Vd)] += acc[mi][ni][r2];
      }
    }
    return;
  }

  // ---- LSTM epilogue: dump preacts to LDS (f16), then pointwise ----
#pragma unroll
  for (int mi = 0; mi < 4; ++mi) {
    int m = wm0 + mi * 16 + (lane >> 4) * 4;
#pragma unroll
    for (int ni = 0; ni < 4; ++ni) {
      int n = wn0 + ni * 16 + (lane & 15);
      half4v hv;
      hv[0] = (_Float16)acc[mi][ni][0];
      hv[1] = (_Float16)acc[mi][ni][1];
      hv[2] = (_Float16)acc[mi][ni][2];
      hv[3] = (_Float16)acc[mi][ni][3];
      *(half4v*)&GT[n * 136 + m] = hv;
    }
  }
  __syncthreads();

  const int bl = tid & 127;             // b within tile
  const int kh = tid >> 7;              // 0/1: which 16-k half
  const int b = b0 + bl;
  const int t = dir ? (Sd - 1 - s) : s;
  const int xv = x[b * Sd + t];
  const float* wrow = wxt + ((size_t)(dir * Vd + xv)) * 2048 + nt * 128;
  float* cc = cst + dir * (Bd * Hd) + b * Hd + nt * 32;
  _Float16* hn = hnext + dir * (Bd * Hd) + b * Hd + nt * 32;
#pragma unroll
  for (int kl = 0; kl < 16; ++kl) {
    int kloc = kh * 16 + kl;
    float4 wv = *(const float4*)&wrow[kloc * 4];
    float g0 = (float)GT[(kloc * 4 + 0) * 136 + bl] + wv.x;
    float g1 = (float)GT[(kloc * 4 + 1) * 136 + bl] + wv.y;
    float g2 = (float)GT[(kloc * 4 + 2) * 136 + bl] + wv.z;
    float g3 = (float)GT[(kloc * 4 + 3) * 136 + bl] + wv.w;
    float gi = sigf(g0), gf = sigf(g1), go = sigf(g2), gg = tanhfast(g3);
    float cn = gf * cc[kloc] + gi * gg;
    cc[kloc] = cn;
    hn[kloc] = (_Float16)(go * tanhfast(cn));
  }
}

extern "C" void kernel_launch(void* const* d_in, const int* in_sizes, int n_in,
                              void* d_out, int out_size, void* d_ws, size_t ws_size,
                              hipStream_t stream) {
  const int* x      = (const int*)d_in[0];
  const float* WxF  = (const float*)d_in[1];
  const float* WhF  = (const float*)d_in[2];
  const float* bxF  = (const float*)d_in[3];
  const float* bhF  = (const float*)d_in[4];
  const float* WxB  = (const float*)d_in[5];
  const float* WhB  = (const float*)d_in[6];
  const float* bxB  = (const float*)d_in[7];
  const float* bhB  = (const float*)d_in[8];
  const float* Wfc  = (const float*)d_in[9];
  const float* bfc  = (const float*)d_in[10];
  float* out = (float*)d_out;

  // ws (floats): wxt[524288] | c[524288] | h f16 (2ph x 2dir x 262144 = 524288 fl)
  //            | wh16 (2097152 halves = 1048576 fl) | wfc16 (131072 halves)
  float* ws = (float*)d_ws;
  float* wxt = ws;
  float* cbuf = ws + 524288;
  _Float16* hbuf = (_Float16*)(ws + 1048576);
  _Float16* wh16 = (_Float16*)(ws + 1572864);
  _Float16* wfc16 = (_Float16*)(ws + 2621440);

  prep_wxt<<<2048, 256, 0, stream>>>(WxF, bxF, bhF, WxB, bxB, bhB, wxt);
  prep_wh16<<<8192, 256, 0, stream>>>(WhF, WhB, wh16);
  prep_wfc16<<<512, 256, 0, stream>>>(Wfc, wfc16);
  init_zero<<<1024, 256, 0, stream>>>(ws + 524288);   // c + both h phases
  init_out<<<16384, 256, 0, stream>>>(bfc, out);

  for (int s = 0; s <= Sd; ++s) {
    int ph = s & 1;
    step_mfma<<<136, 256, 0, stream>>>(
        wxt, x, wh16, wfc16,
        hbuf + (size_t)ph * 524288, hbuf + (size_t)(ph ^ 1) * 524288,
        cbuf, out, s);
  }
}